// Round 7
// baseline (103.444 us; speedup 1.0000x reference)
//
#include <hip/hip_runtime.h>
#include <stdint.h>

#define NB 16
#define NN 25200
#define NCLS 80
#define NROW 85
#define KPRE 1000
#define MAXDET 300
#define CONF_T 0.25f
#define IOU_T 0.45f
#define GCAP 2048

typedef unsigned long long u64;
typedef unsigned int u32;
typedef unsigned short u16;
typedef unsigned char u8;

// Descending-order sortable key: higher score -> smaller key; ties by index.
__device__ __forceinline__ u32 desc_key(float s) {
  u32 u = __float_as_uint(s);
  u = (u & 0x80000000u) ? ~u : (u | 0x80000000u);
  return ~u;
}
__device__ __forceinline__ float inv_key(u32 k) {
  u32 u = ~k;
  u32 o = (u & 0x80000000u) ? (u & 0x7fffffffu) : ~u;
  return __uint_as_float(o);
}

// ---------------- Kernel 0: zero the global histograms ----------------
__global__ __launch_bounds__(1024) void k_zero(u32* __restrict__ gHist) {
  gHist[blockIdx.x * 1024 + threadIdx.x] = 0;
}

// ------- Kernel 1: decode (LDS-staged coalesced) + fused histogram -------
__global__ __launch_bounds__(256) void k_decode(
    const float* __restrict__ pred, float* __restrict__ scores,
    int* __restrict__ clsArr, float4* __restrict__ boxes,
    u32* __restrict__ gHist) {
  __shared__ __align__(16) float lds[4][1360];
  __shared__ u32 h[4096];
  const int tid = threadIdx.x;
  const int wid = tid >> 6, lane = tid & 63;
  const int q = lane & 3, rl = lane >> 2;
  const int img = blockIdx.y;
  const u32 INVB = desc_key(-1.0f) >> 20;
  for (int t = tid; t < 4096; t += 256) h[t] = 0;
  float* L = lds[wid];
  const float* base = pred + (size_t)img * NN * NROW;
  const int waveRow0 = blockIdx.x * 256 + wid * 64;
  const int IMGF = NN * NROW;
  __syncthreads();
  for (int c = 0; c < 4; ++c) {
    const int row0 = waveRow0 + c * 16;
    const int fbase = row0 * NROW;
#pragma unroll
    for (int k = 0; k < 5; ++k) {
      int off = k * 256 + lane * 4;
      int src = (fbase + off + 4 <= IMGF) ? (fbase + off) : 0;
      float4 v;
      __builtin_memcpy(&v, base + src, 16);
      *(float4*)(L + off) = v;
    }
    if (lane < 20) {
      int off = 1280 + lane * 4;
      int src = (fbase + off + 4 <= IMGF) ? (fbase + off) : 0;
      float4 v;
      __builtin_memcpy(&v, base + src, 16);
      *(float4*)(L + off) = v;
    }
    __syncthreads();
    const int row = row0 + rl;
    const bool rowOK = (row < NN);
    const float* R = L + rl * 85;
    float obj = R[4];
    float best = -1.0f;
    int bj = 0;
    const int j0 = q * 20;
#pragma unroll
    for (int jj = 0; jj < 20; ++jj) {
      float v = __fmul_rn(R[5 + j0 + jj], obj);
      if (v > best) { best = v; bj = j0 + jj; }
    }
#pragma unroll
    for (int d = 1; d < 4; d <<= 1) {
      float b2 = __shfl_xor(best, d, 64);
      int j2 = __shfl_xor(bj, d, 64);
      if (b2 > best || (b2 == best && j2 < bj)) { best = b2; bj = j2; }
    }
    bool valid = (best > CONF_T);
    u64 bb = __ballot(q == 0 && rowOK && !valid);
    if (lane == 0 && bb) atomicAdd(&h[INVB], (u32)__popcll(bb));
    if (q == 0 && rowOK) {
      if (valid) atomicAdd(&h[desc_key(best) >> 20], 1u);
      int gid = img * NN + row;
      float x = R[0], y = R[1], w = R[2], hgt = R[3];
      float hx = __fmul_rn(w, 0.5f), hy = __fmul_rn(hgt, 0.5f);
      float4 bx;
      bx.x = __fsub_rn(x, hx);
      bx.y = __fsub_rn(y, hy);
      bx.z = __fadd_rn(x, hx);
      bx.w = __fadd_rn(y, hy);
      scores[gid] = valid ? best : -1.0f;
      clsArr[gid] = bj;
      boxes[gid] = bx;
    }
    __syncthreads();
  }
  for (int t = tid; t < 4096; t += 256) {
    u32 v = h[t];
    if (v) atomicAdd(&gHist[img * 4096 + t], v);
  }
}

// ------- Kernel 2: sortless select + per-class NMS + rank-by-count -------
__global__ __launch_bounds__(1024) void k_select_nms(
    const float* __restrict__ scores, const int* __restrict__ clsArr,
    const float4* __restrict__ boxes, const u32* __restrict__ gHist,
    float* __restrict__ out) {
  const int img = blockIdx.x;
  const int tid = threadIdx.x;
  const int lane = tid & 63;
  const float* sc = scores + (size_t)img * NN;
  const size_t imgN = (size_t)img * NN;

  extern __shared__ __align__(16) char smem[];
  u64* gbuf = (u64*)smem;                     // [2048]  16384 B
  u64* key64 = (u64*)(smem + 16384);          // [1024]   8192 B
  float* bX1 = (float*)(smem + 24576);        // [1024]   4096 B
  float* bY1 = (float*)(smem + 28672);
  float* bX2 = (float*)(smem + 32768);
  float* bY2 = (float*)(smem + 36864);
  u64* svKey = (u64*)(smem + 40960);          // [1024]   8192 B
  u8* dead = (u8*)(smem + 49152);             // [2048]
  u64* tl = (u64*)(smem + 51200);             // [256]   (pre-compact)
  u16* svP = (u16*)(smem + 51200);            // [1024]  (post-NMS, overlays tl)
  u8* clsV = (u8*)(smem + 53248);             // [1024]
  u8* aliveF = (u8*)(smem + 54272);           // [1024]
  u16* clsList = (u16*)(smem + 55296);        // [1024]
  u16* clsSorted = (u16*)(smem + 57344);      // [1024]
  u32* clsCnt = (u32*)(smem + 59392);         // [80]
  u32* clsStart = (u32*)(smem + 59712);       // [81]
  __shared__ u32 subhist[256];
  __shared__ u32 wt[16], wt2[4];
  __shared__ u32 sB, sKr, sThr, sTake, sCnt, sTieCnt, sPcnt, sSvCnt;

  // ---- P0: init + zero output + prefetch keys ----
  float* outImg = out + (size_t)img * MAXDET * 6;
  if (tid == 0) { sCnt = 0; sTieCnt = 0; sPcnt = 0; sSvCnt = 0; }
  aliveF[tid] = 0;
  if (tid < NCLS) clsCnt[tid] = 0;
  dead[tid] = 0;
  dead[tid + 1024] = 0;
  for (int t = tid; t < MAXDET * 6; t += 1024) outImg[t] = 0.0f;
  u32 kk[25];
#pragma unroll
  for (int t = 0; t < 25; ++t) {
    int n = tid + t * 1024;
    kk[t] = (n < NN) ? desc_key(sc[n]) : 0xFFFFFFFFu;
  }

  // ---- A: find 12-bit bucket B of the 1000th key (shfl scan) ----
  uint4 hv = *(const uint4*)(gHist + (size_t)img * 4096 + tid * 4);
  u32 s4 = hv.x + hv.y + hv.z + hv.w;
  u32 incl = s4;
#pragma unroll
  for (int d = 1; d < 64; d <<= 1) {
    u32 o = __shfl_up(incl, (unsigned)d, 64);
    if (lane >= d) incl += o;
  }
  if (lane == 63) wt[tid >> 6] = incl;
  __syncthreads();  // (1)
  {
    u32 woff = 0;
    int w = tid >> 6;
    for (int x = 0; x < w; ++x) woff += wt[x];
    u32 P = woff + incl - s4;  // global exclusive prefix
    if (P < KPRE && P + s4 >= KPRE) {
      u32 cacc = P, b = 3;
      if (cacc + hv.x >= KPRE) b = 0;
      else {
        cacc += hv.x;
        if (cacc + hv.y >= KPRE) b = 1;
        else {
          cacc += hv.y;
          if (cacc + hv.z >= KPRE) b = 2;
          else cacc += hv.z;
        }
      }
      sB = tid * 4 + b;
      sKr = KPRE - cacc;  // needed from bucket B (>=1)
    }
  }
  if (tid < 256) subhist[tid] = 0;
  __syncthreads();  // (2)
  const u32 B = sB;
  const u32 Kr = sKr;

  // ---- A2: 8-bit refinement (bits 19..12) inside bucket B ----
#pragma unroll
  for (int t = 0; t < 25; ++t)
    if ((kk[t] >> 20) == B) atomicAdd(&subhist[(kk[t] >> 12) & 255], 1u);
  __syncthreads();  // (3)
  {
    u32 myc = (tid < 256) ? subhist[tid] : 0;
    u32 inc2 = myc;
#pragma unroll
    for (int d = 1; d < 64; d <<= 1) {
      u32 o = __shfl_up(inc2, (unsigned)d, 64);
      if (lane >= d) inc2 += o;
    }
    if (tid < 256 && lane == 63) wt2[tid >> 6] = inc2;
    __syncthreads();  // (4)
    if (tid < 256) {
      u32 off = 0;
      int w = tid >> 6;
      for (int x = 0; x < w; ++x) off += wt2[x];
      u32 inc = off + inc2, exc = inc - myc;
      if (exc < Kr && inc >= Kr) {
        sThr = (B << 8) | (u32)tid;  // exact 20-bit threshold
        sTake = Kr - exc;            // how many ties to keep
      }
    }
  }
  __syncthreads();  // (5)
  const u32 thr = sThr;
  const u32 take = sTake;

  // ---- C: gather all keys with 20-bit prefix <= thr (wave-aggregated) ----
#pragma unroll
  for (int t = 0; t < 25; ++t) {
    bool g = (kk[t] >> 12) <= thr;
    u64 bb = __ballot(g);
    if (bb) {
      int ldr = __ffsll((long long)bb) - 1;
      u32 base = 0;
      if (lane == ldr) base = atomicAdd(&sCnt, (u32)__popcll(bb));
      base = __shfl(base, ldr, 64);
      if (g) {
        u32 pos = base + (u32)__popcll(bb & ((1ull << lane) - 1ull));
        if (pos < GCAP) gbuf[pos] = ((u64)kk[t] << 32) | (u32)(tid + t * 1024);
      }
    }
  }
  __syncthreads();  // (6)
  const u32 cnt = sCnt < GCAP ? sCnt : GCAP;

  // ---- T: exact tie resolution at the threshold slot ----
  for (u32 t = tid; t < cnt; t += 1024) {
    if ((u32)(gbuf[t] >> 44) == thr) {
      u32 s = atomicAdd(&sTieCnt, 1u);
      if (s < 256) tl[s] = gbuf[t];
    }
  }
  __syncthreads();  // (7)
  if (sTieCnt > take) {
    u32 tc = sTieCnt < 256 ? sTieCnt : 256;
    for (u32 t = tid; t < cnt; t += 1024) {
      if ((u32)(gbuf[t] >> 44) == thr) {
        u64 mine = gbuf[t];
        u32 r = 0;
        for (u32 o = 0; o < tc; ++o) r += (tl[o] < mine) ? 1u : 0u;
        if (r >= take) dead[t] = 1;  // beyond rank 999: excluded entirely
      }
    }
  }
  __syncthreads();  // (8)

  // ---- E: compact participants (exactly KPRE) + fetch cls/box ----
  for (u32 t = tid; t < cnt; t += 1024) {
    if (!dead[t]) {
      u32 p = atomicAdd(&sPcnt, 1u);
      if (p < 1024) {
        u64 e = gbuf[t];
        u32 n = (u32)e;
        int c = clsArr[imgN + n];
        float4 bx = boxes[imgN + n];
        key64[p] = e;
        bX1[p] = bx.x;
        bY1[p] = bx.y;
        bX2[p] = bx.z;
        bY2[p] = bx.w;
        clsV[p] = (u8)c;
        aliveF[p] = (inv_key((u32)(e >> 32)) > CONF_T) ? 1 : 0;
      }
    }
  }
  __syncthreads();  // (9)
  const int Pcnt = (int)(sPcnt < 1024 ? sPcnt : 1024);

  // ---- F: class grouping + in-class rank-by-count (no sort) ----
  int myC = -1;
  u32 arb = 0;
  if (tid < Pcnt) {
    myC = (int)clsV[tid];
    arb = atomicAdd(&clsCnt[myC], 1u);
  }
  __syncthreads();  // (10)
  if (tid == 0) {
    u32 acc = 0;
    for (int c = 0; c < NCLS; ++c) {
      clsStart[c] = acc;
      acc += clsCnt[c];
    }
    clsStart[NCLS] = acc;
  }
  __syncthreads();  // (11)
  if (tid < Pcnt) clsList[clsStart[myC] + arb] = (u16)tid;
  __syncthreads();  // (12)
  if (tid < Pcnt) {
    u32 s = clsStart[myC], e2 = clsStart[myC + 1];
    u64 myk = key64[tid];
    u32 r = 0;
    for (u32 q = s; q < e2; ++q) r += (key64[clsList[q]] < myk) ? 1u : 0u;
    clsSorted[s + r] = (u16)tid;  // class members in exact (key,idx) order
  }
  __syncthreads();  // (13)

  // ---- H: per-class sequential greedy NMS (one wave per class) ----
  {
    const int wid2 = tid >> 6;
    for (int c = wid2; c < NCLS; c += 16) {
      int s = (int)clsStart[c], e2 = (int)clsStart[c + 1];
      float offc = __fmul_rn((float)c, 4096.0f);
      for (int i = s; i < e2; ++i) {
        int ti = (int)clsSorted[i];
        if (!aliveF[ti]) continue;  // wave-uniform
        float ix1 = __fadd_rn(bX1[ti], offc), iy1 = __fadd_rn(bY1[ti], offc);
        float ix2 = __fadd_rn(bX2[ti], offc), iy2 = __fadd_rn(bY2[ti], offc);
        float ia = __fmul_rn(__fsub_rn(ix2, ix1), __fsub_rn(iy2, iy1));
        for (int jb = i + 1 + lane; jb < e2; jb += 64) {
          int tj = (int)clsSorted[jb];
          float jx1 = __fadd_rn(bX1[tj], offc), jy1 = __fadd_rn(bY1[tj], offc);
          float jx2 = __fadd_rn(bX2[tj], offc), jy2 = __fadd_rn(bY2[tj], offc);
          float ja = __fmul_rn(__fsub_rn(jx2, jx1), __fsub_rn(jy2, jy1));
          float xx1 = fmaxf(ix1, jx1), yy1 = fmaxf(iy1, jy1);
          float xx2 = fminf(ix2, jx2), yy2 = fminf(iy2, jy2);
          float ww = fmaxf(__fsub_rn(xx2, xx1), 0.0f);
          float hh = fmaxf(__fsub_rn(yy2, yy1), 0.0f);
          float inter = __fmul_rn(ww, hh);
          float den = __fadd_rn(__fsub_rn(__fadd_rn(ia, ja), inter), 1e-9f);
          if (inter > __fmul_rn(IOU_T, den)) aliveF[tj] = 0;
        }
      }
    }
  }
  __syncthreads();  // (14)

  // ---- S: survivor rank-by-count + write output ----
  if (tid < Pcnt && aliveF[tid]) {
    u32 s = atomicAdd(&sSvCnt, 1u);
    svKey[s] = key64[tid];
    svP[s] = (u16)tid;
  }
  __syncthreads();  // (15)
  const u32 S = sSvCnt;
  for (u32 s = tid; s < S; s += 1024) {
    u64 myk = svKey[s];
    u32 r = 0;
    for (u32 o = 0; o < S; ++o) r += (svKey[o] < myk) ? 1u : 0u;
    if (r < MAXDET) {
      int p = (int)svP[s];
      float* o6 = outImg + (size_t)r * 6;
      o6[0] = bX1[p];
      o6[1] = bY1[p];
      o6[2] = bX2[p];
      o6[3] = bY2[p];
      o6[4] = inv_key((u32)(key64[p] >> 32));
      o6[5] = (float)clsV[p];
    }
  }
}

extern "C" void kernel_launch(void* const* d_in, const int* in_sizes, int n_in,
                              void* d_out, int out_size, void* d_ws, size_t ws_size,
                              hipStream_t stream) {
  const float* pred = (const float*)d_in[0];
  char* ws = (char*)d_ws;
  size_t off = 0;
  float* scores = (float*)(ws + off); off += (size_t)NB * NN * 4;
  int* clsArr = (int*)(ws + off); off += (size_t)NB * NN * 4;
  float4* boxes = (float4*)(ws + off); off += (size_t)NB * NN * 16;
  u32* gHist = (u32*)(ws + off); off += (size_t)NB * 4096 * 4;
  if (off > ws_size) return;

  float* outp = (float*)d_out;
  k_zero<<<NB * 4096 / 1024, 1024, 0, stream>>>(gHist);
  dim3 gridD((NN + 255) / 256, NB);
  k_decode<<<gridD, 256, 0, stream>>>(pred, scores, clsArr, boxes, gHist);
  k_select_nms<<<NB, 1024, 60160, stream>>>(scores, clsArr, boxes, gHist, outp);
}